// Round 8
// baseline (877.804 us; speedup 1.0000x reference)
//
#include <hip/hip_runtime.h>
#include <hip/hip_fp16.h>
#include <hip/hip_fp8.h>
#include <math.h>

// Problem constants (match reference)
#define R_TOT 4096
#define L_LEN 128
#define D_DIM 200
#define A_DIM 20
#define NEGK  2
#define B_SZ  1024
#define NNZ_C 20480
#define RN_TOT (R_TOT*NEGK)
#define S_TOT (R_TOT + RN_TOT)
#define VOCAB_C 32000
#define EPS_ 1e-12f
#define SLOT_CAP 64          // Poisson(20) max bin ~45; 64 is safe
#define NBUCK_BLK 160        // 160*256 = 40960 = 2*NNZ_C

__device__ __forceinline__ float4 unpack4(const uint2 u) {
  union { unsigned v; __half2 h; } c0, c1;
  c0.v = u.x; c1.v = u.y;
  const float2 f0 = __half22float2(c0.h);
  const float2 f1 = __half22float2(c1.h);
  return make_float4(f0.x, f0.y, f1.x, f1.y);
}

// decode 4 packed OCP e4m3 bytes -> float4 (neg-mean path only)
__device__ __forceinline__ float4 unpack_q4(unsigned q) {
  const __half h0((__hip_cvt_fp8_to_halfraw((__hip_fp8_storage_t)( q        & 0xff), __HIP_E4M3)));
  const __half h1((__hip_cvt_fp8_to_halfraw((__hip_fp8_storage_t)((q >> 8)  & 0xff), __HIP_E4M3)));
  const __half h2((__hip_cvt_fp8_to_halfraw((__hip_fp8_storage_t)((q >> 16) & 0xff), __HIP_E4M3)));
  const __half h3((__hip_cvt_fp8_to_halfraw((__hip_fp8_storage_t)((q >> 24) & 0xff), __HIP_E4M3)));
  return make_float4(__half2float(h0), __half2float(h1), __half2float(h2), __half2float(h3));
}

// ---------------- K0: cast emb -> fp16 table + fp8 table; block 0 zeroes bucket counters ----------------
__global__ __launch_bounds__(256) void k_cast(
    const float* __restrict__ emb, ushort* __restrict__ emb_h,
    unsigned char* __restrict__ emb_q, int* __restrict__ cnt)
{
  if (blockIdx.x == 0) {
    for (int i = threadIdx.x; i < 2*B_SZ; i += 256) cnt[i] = 0;
  }
  const int idx = blockIdx.x*256 + threadIdx.x;
  if (idx < (VOCAB_C*D_DIM)/4) {
    const float4 v = reinterpret_cast<const float4*>(emb)[idx];
    ushort4 o;
    o.x = __half_as_ushort(__float2half(v.x));
    o.y = __half_as_ushort(__float2half(v.y));
    o.z = __half_as_ushort(__float2half(v.z));
    o.w = __half_as_ushort(__float2half(v.w));
    reinterpret_cast<ushort4*>(emb_h)[idx] = o;
    const unsigned q =
          (unsigned)__hip_cvt_float_to_fp8(v.x, __HIP_SATFINITE, __HIP_E4M3)
        | ((unsigned)__hip_cvt_float_to_fp8(v.y, __HIP_SATFINITE, __HIP_E4M3) << 8)
        | ((unsigned)__hip_cvt_float_to_fp8(v.z, __HIP_SATFINITE, __HIP_E4M3) << 16)
        | ((unsigned)__hip_cvt_float_to_fp8(v.w, __HIP_SATFINITE, __HIP_E4M3) << 24);
    reinterpret_cast<unsigned*>(emb_q)[idx] = q;
  }
}

// ---------------- K1: combined means (pos fp16 / neg fp8) + piggybacked sparse bucketing ----------------
// One 12448-block launch: max independent blocks co-resident (round-7 lesson:
// splitting this into serial passes regressed 17%).
__global__ __launch_bounds__(256, 8) void k_means2(
    const int* __restrict__ hist, const int* __restrict__ neg,
    const ushort* __restrict__ emb_h, const unsigned char* __restrict__ emb_q,
    float* __restrict__ ys_all, float* __restrict__ zn_all,
    const int* __restrict__ uidx, const float* __restrict__ uval,
    const int* __restrict__ iidx, const float* __restrict__ ival,
    int* __restrict__ cnt, int* __restrict__ scol, float* __restrict__ sval)
{
  const int s = blockIdx.x;
  const int tid = threadIdx.x, lane = tid & 63, wv = tid >> 6;

  if (s >= S_TOT) {
    // ---- bucket pass: one thread per nnz entry (user then item) ----
    const int g = (s - S_TOT)*256 + tid;
    if (g < NNZ_C) {
      const int b = uidx[g];
      const int slot = atomicAdd(&cnt[b], 1);
      if (slot < SLOT_CAP) {
        scol[b*SLOT_CAP + slot] = uidx[NNZ_C + g];
        sval[b*SLOT_CAP + slot] = uval[g];
      }
    } else {
      const int g2 = g - NNZ_C;
      const int b = iidx[g2];
      const int slot = atomicAdd(&cnt[B_SZ + b], 1);
      if (slot < SLOT_CAP) {
        scol[(B_SZ + b)*SLOT_CAP + slot] = iidx[NNZ_C + g2];
        sval[(B_SZ + b)*SLOT_CAP + slot] = ival[g2];
      }
    }
    return;
  }

  __shared__ int widx[L_LEN];
  __shared__ __align__(16) float part[4][D_DIM];
  const bool is_pos = (s < R_TOT);
  const int* src = is_pos ? (hist + (size_t)s*L_LEN)
                          : (neg + (size_t)(s - R_TOT)*L_LEN);
  if (tid < L_LEN) widx[tid] = src[tid];
  __syncthreads();

  float4 a0 = {0,0,0,0}, a1 = {0,0,0,0}, a2 = {0,0,0,0}, a3 = {0,0,0,0};
  if (lane < 50) {
    const int l0 = wv*32;
    if (is_pos) {
      // fp16 gathers (numerics-relevant: y_s -> attention weights), ILP-4
      #pragma unroll
      for (int g = 0; g < 8; ++g) {
        const int l = l0 + g*4;
        const float4 v0 = unpack4(*reinterpret_cast<const uint2*>(emb_h + (size_t)widx[l  ]*D_DIM + 4*lane));
        const float4 v1 = unpack4(*reinterpret_cast<const uint2*>(emb_h + (size_t)widx[l+1]*D_DIM + 4*lane));
        const float4 v2 = unpack4(*reinterpret_cast<const uint2*>(emb_h + (size_t)widx[l+2]*D_DIM + 4*lane));
        const float4 v3 = unpack4(*reinterpret_cast<const uint2*>(emb_h + (size_t)widx[l+3]*D_DIM + 4*lane));
        a0.x += v0.x; a0.y += v0.y; a0.z += v0.z; a0.w += v0.w;
        a1.x += v1.x; a1.y += v1.y; a1.z += v1.z; a1.w += v1.w;
        a2.x += v2.x; a2.y += v2.y; a2.z += v2.z; a2.w += v2.w;
        a3.x += v3.x; a3.y += v3.y; a3.z += v3.z; a3.w += v3.w;
      }
    } else {
      // fp8 gathers (feeds only abae margin loss; table 6.4 MB ~ L2-resident), ILP-4
      #pragma unroll
      for (int g = 0; g < 8; ++g) {
        const int l = l0 + g*4;
        const unsigned q0 = *reinterpret_cast<const unsigned*>(emb_q + (size_t)widx[l  ]*D_DIM + 4*lane);
        const unsigned q1 = *reinterpret_cast<const unsigned*>(emb_q + (size_t)widx[l+1]*D_DIM + 4*lane);
        const unsigned q2 = *reinterpret_cast<const unsigned*>(emb_q + (size_t)widx[l+2]*D_DIM + 4*lane);
        const unsigned q3 = *reinterpret_cast<const unsigned*>(emb_q + (size_t)widx[l+3]*D_DIM + 4*lane);
        const float4 v0 = unpack_q4(q0);
        const float4 v1 = unpack_q4(q1);
        const float4 v2 = unpack_q4(q2);
        const float4 v3 = unpack_q4(q3);
        a0.x += v0.x; a0.y += v0.y; a0.z += v0.z; a0.w += v0.w;
        a1.x += v1.x; a1.y += v1.y; a1.z += v1.z; a1.w += v1.w;
        a2.x += v2.x; a2.y += v2.y; a2.z += v2.z; a2.w += v2.w;
        a3.x += v3.x; a3.y += v3.y; a3.z += v3.z; a3.w += v3.w;
      }
    }
    a0.x += a1.x + a2.x + a3.x; a0.y += a1.y + a2.y + a3.y;
    a0.z += a1.z + a2.z + a3.z; a0.w += a1.w + a2.w + a3.w;
    *reinterpret_cast<float4*>(&part[wv][4*lane]) = a0;
  }
  __syncthreads();
  float* dst = is_pos ? (ys_all + (size_t)s*D_DIM)
                      : (zn_all + (size_t)(s - R_TOT)*D_DIM);
  if (tid < D_DIM)
    dst[tid] = (part[0][tid] + part[1][tid] + part[2][tid] + part[3][tid]) * (1.0f/128.0f);
}

// ---------------- K2: V = Y @ Wm (16 reviews/block) ----------------
#define KB_RT 16
__global__ __launch_bounds__(256, 2) void k_matvec(
    const float* __restrict__ ys_all, const float* __restrict__ Wm,
    float* __restrict__ vv_all)
{
  __shared__ float ysl[KB_RT][D_DIM];
  const int r0 = blockIdx.x * KB_RT;
  const int tid = threadIdx.x;
  for (int i = tid; i < KB_RT*D_DIM; i += 256)
    ysl[i / D_DIM][i % D_DIM] = ys_all[(size_t)r0*D_DIM + i];
  __syncthreads();
  if (tid < D_DIM) {
    float acc[KB_RT];
    #pragma unroll
    for (int r = 0; r < KB_RT; ++r) acc[r] = 0.f;
    #pragma unroll 4
    for (int k = 0; k < D_DIM; ++k) {
      const float w = Wm[k*D_DIM + tid];
      #pragma unroll
      for (int r = 0; r < KB_RT; ++r) acc[r] += ysl[r][k] * w;
    }
    #pragma unroll
    for (int r = 0; r < KB_RT; ++r)
      vv_all[(size_t)(r0 + r)*D_DIM + tid] = acc[r];
  }
}

// ---------------- K3: dx -> softmax -> z_s -> p_t -> r_s -> c1 (round-5 version, known 115 us) ----------------
__global__ __launch_bounds__(256, 8) void k_attn(
    const int* __restrict__ hist, const ushort* __restrict__ emb_h,
    const float* __restrict__ vv_all, const float* __restrict__ Ww,
    const float* __restrict__ bw, const float* __restrict__ Wt,
    float* __restrict__ rs_out, float* __restrict__ c1_out,
    float* __restrict__ rsinv_out)
{
  __shared__ int widx[L_LEN];
  __shared__ __align__(16) float ax[L_LEN];
  __shared__ __align__(16) float vvl[D_DIM];
  __shared__ float zs[D_DIM];
  __shared__ float ptile[160];
  __shared__ float red[40];
  const int r = blockIdx.x;
  const int tid = threadIdx.x, lane = tid & 63, wv = tid >> 6;

  if (tid < L_LEN) widx[tid] = hist[r*L_LEN + tid];
  if (tid < D_DIM) vvl[tid] = vv_all[(size_t)r*D_DIM + tid];
  __syncthreads();

  // dx[l] = e_w[l,:].v — wave-per-row, fp16 uint2 loads, butterfly
  {
    float4 v4 = {0.f,0.f,0.f,0.f};
    if (lane < 50) v4 = *reinterpret_cast<const float4*>(vvl + 4*lane);
    for (int l = wv; l < L_LEN; l += 4) {
      float a = 0.f;
      if (lane < 50) {
        const float4 e4 = unpack4(*reinterpret_cast<const uint2*>(
            emb_h + (size_t)widx[l]*D_DIM + 4*lane));
        a = e4.x*v4.x + e4.y*v4.y + e4.z*v4.z + e4.w*v4.w;
      }
      #pragma unroll
      for (int o = 32; o > 0; o >>= 1) a += __shfl_xor(a, o);
      if (lane == 0) ax[l] = a;
    }
  }
  __syncthreads();

  // softmax over 128 (wave0 reduces)
  if (tid < 64) {
    float m = fmaxf(ax[tid], ax[tid+64]);
    #pragma unroll
    for (int o = 32; o > 0; o >>= 1) m = fmaxf(m, __shfl_xor(m, o));
    if (tid == 0) red[0] = m;
  }
  __syncthreads();
  const float M = red[0];
  if (tid < L_LEN) ax[tid] = expf(ax[tid] - M);
  __syncthreads();
  if (tid < 64) {
    float s = ax[tid] + ax[tid+64];
    #pragma unroll
    for (int o = 32; o > 0; o >>= 1) s += __shfl_xor(s, o);
    if (tid == 0) red[1] = s;
  }
  __syncthreads();
  const float Sinv = 1.0f / red[1];
  if (tid < L_LEN) ax[tid] *= Sinv;
  __syncthreads();

  // z_s[d] = sum_i ax[i]*flat[128d+i]; every 4-half group is in-row & 8B-aligned
  {
    const int lh = lane & 31;
    const float4 ax4 = *reinterpret_cast<const float4*>(ax + 4*lh);
    for (int dp = wv; dp < 100; dp += 4) {
      const int d = 2*dp + (lane >> 5);
      const int f = (d << 7) + 4*lh;
      const float4 e4 = unpack4(*reinterpret_cast<const uint2*>(
          emb_h + (size_t)widx[f/200]*D_DIM + (f % 200)));
      float a = e4.x*ax4.x + e4.y*ax4.y + e4.z*ax4.z + e4.w*ax4.w;
      #pragma unroll
      for (int o = 16; o > 0; o >>= 1) a += __shfl_xor(a, o);
      if (lh == 0) zs[d] = a;
    }
  }
  __syncthreads();

  // p_t[a] = z_s . Ww[a,:] + bw[a]  — 8x20 partials
  if (tid < 160) {
    const int a = tid % 20, j = tid / 20;
    float s = 0.f;
    #pragma unroll
    for (int i = 0; i < 25; ++i) {
      const int d = j + 8*i;
      s += zs[d] * Ww[a*D_DIM + d];
    }
    ptile[tid] = s;
  }
  __syncthreads();
  if (tid < A_DIM) {
    float s = bw[tid];
    #pragma unroll
    for (int j = 0; j < 8; ++j) s += ptile[j*20 + tid];
    red[2 + tid] = s;
  }
  __syncthreads();

  // r_s[d] = sum_a p_t[a]*Wt[d,a]; norms for c1
  float rsd = 0.f, zsd = 0.f;
  if (tid < D_DIM) {
    float acc = 0.f;
    #pragma unroll
    for (int a = 0; a < A_DIM; ++a) acc += red[2+a] * Wt[tid*A_DIM + a];
    rsd = acc; zsd = zs[tid];
    rs_out[(size_t)r*D_DIM + tid] = acc;
  }
  float a0 = rsd*rsd, a1 = zsd*zsd, a2 = rsd*zsd;
  #pragma unroll
  for (int o = 32; o > 0; o >>= 1) {
    a0 += __shfl_xor(a0, o); a1 += __shfl_xor(a1, o); a2 += __shfl_xor(a2, o);
  }
  if ((tid & 63) == 0) { red[24+wv] = a0; red[28+wv] = a1; red[32+wv] = a2; }
  __syncthreads();
  if (tid == 0) {
    const float s0 = red[24]+red[25]+red[26]+red[27];
    const float s1 = red[28]+red[29]+red[30]+red[31];
    const float s2 = red[32]+red[33]+red[34]+red[35];
    const float nr = fmaxf(sqrtf(s0), EPS_);
    const float nz = fmaxf(sqrtf(s1), EPS_);
    c1_out[r] = s2 / (nr * nz);
    rsinv_out[r] = 1.0f / nr;
  }
}

// ---------------- K4: c2 + margin loss from precomputed z_n ----------------
__global__ __launch_bounds__(64, 16) void k_c2(
    const float* __restrict__ zn_all, const float* __restrict__ rs,
    const float* __restrict__ c1, const float* __restrict__ rsinv,
    float* __restrict__ abae)
{
  const int rn = blockIdx.x;
  const int r = rn >> 1;              // NEG = 2
  const int lane = threadIdx.x;
  float s0 = 0.f, s1 = 0.f;
  if (lane < 50) {
    const float4 z4 = *reinterpret_cast<const float4*>(zn_all + (size_t)rn*D_DIM + 4*lane);
    const float4 r4 = *reinterpret_cast<const float4*>(rs + (size_t)r*D_DIM + 4*lane);
    s0 = z4.x*z4.x + z4.y*z4.y + z4.z*z4.z + z4.w*z4.w;
    s1 = z4.x*r4.x + z4.y*r4.y + z4.z*r4.z + z4.w*r4.w;
  }
  #pragma unroll
  for (int o = 32; o > 0; o >>= 1) { s0 += __shfl_xor(s0,o); s1 += __shfl_xor(s1,o); }
  if (lane == 0) {
    const float nz = fmaxf(sqrtf(s0), EPS_);
    abae[rn] = fmaxf((s1/nz)*rsinv[r] - c1[r] + 1.0f, 0.0f);
  }
}

// ---------------- K5: merged segment-sum apply + FM (one block per b) ----------------
__global__ __launch_bounds__(512) void k_aggfm(
    const int* __restrict__ cnt, const int* __restrict__ scol,
    const float* __restrict__ sval, const float* __restrict__ rs,
    const float* __restrict__ fcw, const float* __restrict__ V,
    float* __restrict__ uae, float* __restrict__ iae,
    float* __restrict__ linb, float* __restrict__ quadb)
{
  __shared__ __align__(16) float ivec[2*D_DIM];
  __shared__ float redw[8];
  __shared__ float qpart[10];
  const int b = blockIdx.x;
  const int tid = threadIdx.x, lane = tid & 63, wv = tid >> 6;

  if (tid < D_DIM) {
    int n = cnt[b]; n = n < SLOT_CAP ? n : SLOT_CAP;
    const int* cols = scol + (size_t)b*SLOT_CAP;
    const float* vals = sval + (size_t)b*SLOT_CAP;
    float acc = 0.f;
    for (int j = 0; j < n; ++j) acc += vals[j] * rs[(size_t)cols[j]*D_DIM + tid];
    ivec[tid] = acc;
    uae[(size_t)b*D_DIM + tid] = acc;
  } else if (tid >= 256 && tid < 256 + D_DIM) {
    const int t = tid - 256;
    int n = cnt[B_SZ + b]; n = n < SLOT_CAP ? n : SLOT_CAP;
    const int* cols = scol + (size_t)(B_SZ + b)*SLOT_CAP;
    const float* vals = sval + (size_t)(B_SZ + b)*SLOT_CAP;
    float acc = 0.f;
    for (int j = 0; j < n; ++j) acc += vals[j] * rs[(size_t)cols[j]*D_DIM + t];
    ivec[D_DIM + t] = acc;
    iae[(size_t)b*D_DIM + t] = acc;
  }
  __syncthreads();

  float lv = 0.f;
  if (tid < 2*D_DIM) lv = ivec[tid] * fcw[tid];
  #pragma unroll
  for (int o = 32; o > 0; o >>= 1) lv += __shfl_xor(lv, o);
  if (lane == 0) redw[wv] = lv;

  {
    const int k = wv;
    float s1 = 0.f, s2 = 0.f;
    for (int f = lane; f < 2*D_DIM; f += 64) {
      const float x = ivec[f];
      const float vk = V[f*10 + k];
      s1 += x*vk; s2 += x*x*vk*vk;
    }
    #pragma unroll
    for (int o = 32; o > 0; o >>= 1) { s1 += __shfl_xor(s1,o); s2 += __shfl_xor(s2,o); }
    if (lane == 0) qpart[k] = s1*s1 - s2;
  }
  if (wv < 2) {
    const int k = 8 + wv;
    float s1 = 0.f, s2 = 0.f;
    for (int f = lane; f < 2*D_DIM; f += 64) {
      const float x = ivec[f];
      const float vk = V[f*10 + k];
      s1 += x*vk; s2 += x*x*vk*vk;
    }
    #pragma unroll
    for (int o = 32; o > 0; o >>= 1) { s1 += __shfl_xor(s1,o); s2 += __shfl_xor(s2,o); }
    if (lane == 0) qpart[k] = s1*s1 - s2;
  }
  __syncthreads();
  if (tid == 0) {
    float lin = 0.f;
    #pragma unroll
    for (int i = 0; i < 8; ++i) lin += redw[i];
    float q = 0.f;
    #pragma unroll
    for (int i = 0; i < 10; ++i) q += qpart[i];
    linb[b] = lin; quadb[b] = q;
  }
}

// ---------------- K6: fused quad-reduce + prediction + all final scalars ----------------
__global__ __launch_bounds__(1024) void k_final2(
    const float* __restrict__ quadb, const float* __restrict__ linb,
    const float* __restrict__ fcb, const int* __restrict__ user,
    const int* __restrict__ item, const float* __restrict__ busers,
    const float* __restrict__ bitems, const float* __restrict__ label,
    const float* __restrict__ Wt, const float* __restrict__ abae,
    float* __restrict__ pred, float* __restrict__ rl, float* __restrict__ obj)
{
  __shared__ float sA[16], sB[16], sC[16];
  __shared__ float cninv[A_DIM];
  __shared__ float quad_s;
  const int tid = threadIdx.x;
  const int lane = tid & 63;
  const int wv = tid >> 6;

  float q = quadb[tid];
  #pragma unroll
  for (int o = 32; o > 0; o >>= 1) q += __shfl_xor(q, o);
  if (lane == 0) sA[wv] = q;

  if (tid < A_DIM) {
    float s = 0.f;
    for (int d = 0; d < D_DIM; ++d) { const float w = Wt[d*A_DIM + tid]; s += w*w; }
    cninv[tid] = 1.0f / fmaxf(sqrtf(s), EPS_);
  }
  __syncthreads();
  if (wv == 0) {
    float s = (lane < 16) ? sA[lane] : 0.f;
    #pragma unroll
    for (int o = 32; o > 0; o >>= 1) s += __shfl_xor(s, o);
    if (lane == 0) quad_s = s;
  }
  __syncthreads();

  const float p = 0.5f*quad_s + linb[tid] + fcb[0]
                + busers[user[tid]] + bitems[item[tid]];
  pred[tid] = p;
  const float dd = p - label[tid];
  const float myrl = dd*dd;
  rl[tid] = myrl;

  float u = 0.f;
  if (tid < 400) {
    const int a = tid / 20, c = tid % 20;
    float dot = 0.f;
    for (int d = 0; d < D_DIM; ++d) dot += Wt[d*A_DIM + a]*Wt[d*A_DIM + c];
    const float g = dot*cninv[a]*cninv[c] - (a==c ? 1.0f : 0.0f);
    u = g*g;
  }
  float js = 0.f;
  #pragma unroll
  for (int j = 0; j < 8; ++j) js += abae[tid + 1024*j];
  float ms = myrl;

  #pragma unroll
  for (int o = 32; o > 0; o >>= 1) {
    u += __shfl_xor(u,o); js += __shfl_xor(js,o); ms += __shfl_xor(ms,o);
  }
  if (lane == 0) { sA[wv] = u; sB[wv] = js; sC[wv] = ms; }
  __syncthreads();
  if (tid == 0) {
    float U = 0.f, J = 0.f, Ms = 0.f;
    for (int i = 0; i < 16; ++i) { U += sA[i]; J += sB[i]; Ms += sC[i]; }
    obj[0] = Ms/1024.0f + 0.01f*(J/8192.0f) + 0.01f*(U/400.0f);
  }
}

extern "C" void kernel_launch(void* const* d_in, const int* in_sizes, int n_in,
                              void* d_out, int out_size, void* d_ws, size_t ws_size,
                              hipStream_t stream) {
  const int*   hist   = (const int*)  d_in[0];
  const int*   neg    = (const int*)  d_in[1];
  const int*   user   = (const int*)  d_in[2];
  const int*   item   = (const int*)  d_in[3];
  const float* label  = (const float*)d_in[4];
  const int*   uidx   = (const int*)  d_in[5];
  const float* uval   = (const float*)d_in[6];
  const int*   iidx   = (const int*)  d_in[7];
  const float* ival   = (const float*)d_in[8];
  const float* emb    = (const float*)d_in[9];
  const float* Wm     = (const float*)d_in[10];
  const float* Ww     = (const float*)d_in[11];
  const float* bw     = (const float*)d_in[12];
  const float* Wt     = (const float*)d_in[13];
  const float* fcw    = (const float*)d_in[14];
  const float* fcb    = (const float*)d_in[15];
  const float* V      = (const float*)d_in[16];
  const float* busers = (const float*)d_in[17];
  const float* bitems = (const float*)d_in[18];

  float* out  = (float*)d_out;
  float* obj  = out;                       // 1
  float* rl   = out + 1;                   // 1024
  float* abae = out + 1 + B_SZ;            // 8192
  float* pred = out + 1 + B_SZ + RN_TOT;   // 1024
  float* uae  = pred + B_SZ;               // 204800
  float* iae  = uae + (size_t)B_SZ*D_DIM;  // 204800

  float* ws     = (float*)d_ws;
  float* rs     = ws;                              // R*D
  float* ys_all = rs + (size_t)R_TOT*D_DIM;        // R*D
  float* zn_all = ys_all + (size_t)R_TOT*D_DIM;    // RN*D
  float* vv_all = zn_all + (size_t)RN_TOT*D_DIM;   // R*D
  float* c1     = vv_all + (size_t)R_TOT*D_DIM;    // R
  float* rsinv  = c1 + R_TOT;                      // R
  float* linb   = rsinv + R_TOT;                   // B
  float* quadb  = linb + B_SZ;                     // B
  float* sval   = quadb + B_SZ;                    // 2*B*SLOT_CAP floats
  int*   scol   = (int*)(sval + (size_t)2*B_SZ*SLOT_CAP);   // 2*B*SLOT_CAP ints
  int*   cnt    = scol + (size_t)2*B_SZ*SLOT_CAP;           // 2*B ints
  ushort* emb_h = (ushort*)(cnt + 2*B_SZ);                  // VOCAB*D halves
  unsigned char* emb_q = (unsigned char*)(emb_h + (size_t)VOCAB_C*D_DIM); // VOCAB*D fp8

  const int cast_blocks = (VOCAB_C*D_DIM/4 + 255)/256;      // 6250

  k_cast  <<<cast_blocks, 256, 0, stream>>>(emb, emb_h, emb_q, cnt);
  k_means2<<<S_TOT + NBUCK_BLK, 256, 0, stream>>>(hist, neg, emb_h, emb_q,
                                                  ys_all, zn_all,
                                                  uidx, uval, iidx, ival,
                                                  cnt, scol, sval);
  k_matvec<<<R_TOT/KB_RT, 256, 0, stream>>>(ys_all, Wm, vv_all);
  k_attn  <<<R_TOT, 256, 0, stream>>>(hist, emb_h, vv_all, Ww, bw, Wt, rs, c1, rsinv);
  k_c2    <<<RN_TOT, 64, 0, stream>>>(zn_all, rs, c1, rsinv, abae);
  k_aggfm <<<B_SZ, 512, 0, stream>>>(cnt, scol, sval, rs, fcw, V,
                                     uae, iae, linb, quadb);
  k_final2<<<1, 1024, 0, stream>>>(quadb, linb, fcb, user, item, busers, bitems,
                                   label, Wt, abae, pred, rl, obj);
}

// Round 9
// 463.216 us; speedup vs baseline: 1.8950x; 1.8950x over previous
//
#include <hip/hip_runtime.h>
#include <hip/hip_fp16.h>
#include <math.h>

// Problem constants (match reference)
#define R_TOT 4096
#define L_LEN 128
#define D_DIM 200
#define A_DIM 20
#define NEGK  2
#define B_SZ  1024
#define NNZ_C 20480
#define RN_TOT (R_TOT*NEGK)
#define S_TOT (R_TOT + RN_TOT)
#define VOCAB_C 32000
#define EPS_ 1e-12f
#define SLOT_CAP 64          // Poisson(20) max bin ~45; 64 is safe
#define NBUCK_BLK 160        // 160*256 = 40960 = 2*NNZ_C

__device__ __forceinline__ float4 unpack4(const uint2 u) {
  union { unsigned v; __half2 h; } c0, c1;
  c0.v = u.x; c1.v = u.y;
  const float2 f0 = __half22float2(c0.h);
  const float2 f1 = __half22float2(c1.h);
  return make_float4(f0.x, f0.y, f1.x, f1.y);
}

// ---------------- K0: cast emb -> fp16 table; block 0 also zeroes bucket counters ----------------
__global__ __launch_bounds__(256) void k_cast(
    const float* __restrict__ emb, ushort* __restrict__ emb_h, int* __restrict__ cnt)
{
  if (blockIdx.x == 0) {
    for (int i = threadIdx.x; i < 2*B_SZ; i += 256) cnt[i] = 0;
  }
  const int idx = blockIdx.x*256 + threadIdx.x;
  if (idx < (VOCAB_C*D_DIM)/4) {
    const float4 v = reinterpret_cast<const float4*>(emb)[idx];
    ushort4 o;
    o.x = __half_as_ushort(__float2half(v.x));
    o.y = __half_as_ushort(__float2half(v.y));
    o.z = __half_as_ushort(__float2half(v.z));
    o.w = __half_as_ushort(__float2half(v.w));
    reinterpret_cast<ushort4*>(emb_h)[idx] = o;
  }
}

// ---------------- K1: combined means (pos+neg, fp16, ILP-4) + piggybacked sparse bucketing ----------------
// One 12448-block launch: max independent blocks co-resident (round-7 lesson:
// splitting into serial passes regressed 17%). fp8 neg-table experiment (round 8)
// regressed 2.3x: gfx950 fp8 cvt header path generates scratch traffic (672 MB writes).
__global__ __launch_bounds__(256, 8) void k_means2(
    const int* __restrict__ hist, const int* __restrict__ neg,
    const ushort* __restrict__ emb_h,
    float* __restrict__ ys_all, float* __restrict__ zn_all,
    const int* __restrict__ uidx, const float* __restrict__ uval,
    const int* __restrict__ iidx, const float* __restrict__ ival,
    int* __restrict__ cnt, int* __restrict__ scol, float* __restrict__ sval)
{
  const int s = blockIdx.x;
  const int tid = threadIdx.x, lane = tid & 63, wv = tid >> 6;

  if (s >= S_TOT) {
    // ---- bucket pass: one thread per nnz entry (user then item) ----
    const int g = (s - S_TOT)*256 + tid;
    if (g < NNZ_C) {
      const int b = uidx[g];
      const int slot = atomicAdd(&cnt[b], 1);
      if (slot < SLOT_CAP) {
        scol[b*SLOT_CAP + slot] = uidx[NNZ_C + g];
        sval[b*SLOT_CAP + slot] = uval[g];
      }
    } else {
      const int g2 = g - NNZ_C;
      const int b = iidx[g2];
      const int slot = atomicAdd(&cnt[B_SZ + b], 1);
      if (slot < SLOT_CAP) {
        scol[(B_SZ + b)*SLOT_CAP + slot] = iidx[NNZ_C + g2];
        sval[(B_SZ + b)*SLOT_CAP + slot] = ival[g2];
      }
    }
    return;
  }

  __shared__ int widx[L_LEN];
  __shared__ __align__(16) float part[4][D_DIM];
  const bool is_pos = (s < R_TOT);
  const int* src = is_pos ? (hist + (size_t)s*L_LEN)
                          : (neg + (size_t)(s - R_TOT)*L_LEN);
  if (tid < L_LEN) widx[tid] = src[tid];
  __syncthreads();

  float4 a0 = {0,0,0,0}, a1 = {0,0,0,0}, a2 = {0,0,0,0}, a3 = {0,0,0,0};
  if (lane < 50) {
    const int l0 = wv*32;
    #pragma unroll
    for (int g = 0; g < 8; ++g) {
      const int l = l0 + g*4;
      const float4 v0 = unpack4(*reinterpret_cast<const uint2*>(emb_h + (size_t)widx[l  ]*D_DIM + 4*lane));
      const float4 v1 = unpack4(*reinterpret_cast<const uint2*>(emb_h + (size_t)widx[l+1]*D_DIM + 4*lane));
      const float4 v2 = unpack4(*reinterpret_cast<const uint2*>(emb_h + (size_t)widx[l+2]*D_DIM + 4*lane));
      const float4 v3 = unpack4(*reinterpret_cast<const uint2*>(emb_h + (size_t)widx[l+3]*D_DIM + 4*lane));
      a0.x += v0.x; a0.y += v0.y; a0.z += v0.z; a0.w += v0.w;
      a1.x += v1.x; a1.y += v1.y; a1.z += v1.z; a1.w += v1.w;
      a2.x += v2.x; a2.y += v2.y; a2.z += v2.z; a2.w += v2.w;
      a3.x += v3.x; a3.y += v3.y; a3.z += v3.z; a3.w += v3.w;
    }
    a0.x += a1.x + a2.x + a3.x; a0.y += a1.y + a2.y + a3.y;
    a0.z += a1.z + a2.z + a3.z; a0.w += a1.w + a2.w + a3.w;
    *reinterpret_cast<float4*>(&part[wv][4*lane]) = a0;
  }
  __syncthreads();
  float* dst = is_pos ? (ys_all + (size_t)s*D_DIM)
                      : (zn_all + (size_t)(s - R_TOT)*D_DIM);
  if (tid < D_DIM)
    dst[tid] = (part[0][tid] + part[1][tid] + part[2][tid] + part[3][tid]) * (1.0f/128.0f);
}

// ---------------- K2: V = Y @ Wm (16 reviews/block) ----------------
#define KB_RT 16
__global__ __launch_bounds__(256, 2) void k_matvec(
    const float* __restrict__ ys_all, const float* __restrict__ Wm,
    float* __restrict__ vv_all)
{
  __shared__ float ysl[KB_RT][D_DIM];
  const int r0 = blockIdx.x * KB_RT;
  const int tid = threadIdx.x;
  for (int i = tid; i < KB_RT*D_DIM; i += 256)
    ysl[i / D_DIM][i % D_DIM] = ys_all[(size_t)r0*D_DIM + i];
  __syncthreads();
  if (tid < D_DIM) {
    float acc[KB_RT];
    #pragma unroll
    for (int r = 0; r < KB_RT; ++r) acc[r] = 0.f;
    #pragma unroll 4
    for (int k = 0; k < D_DIM; ++k) {
      const float w = Wm[k*D_DIM + tid];
      #pragma unroll
      for (int r = 0; r < KB_RT; ++r) acc[r] += ysl[r][k] * w;
    }
    #pragma unroll
    for (int r = 0; r < KB_RT; ++r)
      vv_all[(size_t)(r0 + r)*D_DIM + tid] = acc[r];
  }
}

// ---------------- K3: dx -> softmax -> z_s -> p_t -> r_s -> c1 (round-5 version, known-good) ----------------
__global__ __launch_bounds__(256, 8) void k_attn(
    const int* __restrict__ hist, const ushort* __restrict__ emb_h,
    const float* __restrict__ vv_all, const float* __restrict__ Ww,
    const float* __restrict__ bw, const float* __restrict__ Wt,
    float* __restrict__ rs_out, float* __restrict__ c1_out,
    float* __restrict__ rsinv_out)
{
  __shared__ int widx[L_LEN];
  __shared__ __align__(16) float ax[L_LEN];
  __shared__ __align__(16) float vvl[D_DIM];
  __shared__ float zs[D_DIM];
  __shared__ float ptile[160];
  __shared__ float red[40];
  const int r = blockIdx.x;
  const int tid = threadIdx.x, lane = tid & 63, wv = tid >> 6;

  if (tid < L_LEN) widx[tid] = hist[r*L_LEN + tid];
  if (tid < D_DIM) vvl[tid] = vv_all[(size_t)r*D_DIM + tid];
  __syncthreads();

  // dx[l] = e_w[l,:].v — wave-per-row, fp16 uint2 loads, butterfly
  {
    float4 v4 = {0.f,0.f,0.f,0.f};
    if (lane < 50) v4 = *reinterpret_cast<const float4*>(vvl + 4*lane);
    for (int l = wv; l < L_LEN; l += 4) {
      float a = 0.f;
      if (lane < 50) {
        const float4 e4 = unpack4(*reinterpret_cast<const uint2*>(
            emb_h + (size_t)widx[l]*D_DIM + 4*lane));
        a = e4.x*v4.x + e4.y*v4.y + e4.z*v4.z + e4.w*v4.w;
      }
      #pragma unroll
      for (int o = 32; o > 0; o >>= 1) a += __shfl_xor(a, o);
      if (lane == 0) ax[l] = a;
    }
  }
  __syncthreads();

  // softmax over 128 (wave0 reduces)
  if (tid < 64) {
    float m = fmaxf(ax[tid], ax[tid+64]);
    #pragma unroll
    for (int o = 32; o > 0; o >>= 1) m = fmaxf(m, __shfl_xor(m, o));
    if (tid == 0) red[0] = m;
  }
  __syncthreads();
  const float M = red[0];
  if (tid < L_LEN) ax[tid] = expf(ax[tid] - M);
  __syncthreads();
  if (tid < 64) {
    float s = ax[tid] + ax[tid+64];
    #pragma unroll
    for (int o = 32; o > 0; o >>= 1) s += __shfl_xor(s, o);
    if (tid == 0) red[1] = s;
  }
  __syncthreads();
  const float Sinv = 1.0f / red[1];
  if (tid < L_LEN) ax[tid] *= Sinv;
  __syncthreads();

  // z_s[d] = sum_i ax[i]*flat[128d+i]; every 4-half group is in-row & 8B-aligned
  {
    const int lh = lane & 31;
    const float4 ax4 = *reinterpret_cast<const float4*>(ax + 4*lh);
    for (int dp = wv; dp < 100; dp += 4) {
      const int d = 2*dp + (lane >> 5);
      const int f = (d << 7) + 4*lh;
      const float4 e4 = unpack4(*reinterpret_cast<const uint2*>(
          emb_h + (size_t)widx[f/200]*D_DIM + (f % 200)));
      float a = e4.x*ax4.x + e4.y*ax4.y + e4.z*ax4.z + e4.w*ax4.w;
      #pragma unroll
      for (int o = 16; o > 0; o >>= 1) a += __shfl_xor(a, o);
      if (lh == 0) zs[d] = a;
    }
  }
  __syncthreads();

  // p_t[a] = z_s . Ww[a,:] + bw[a]  — 8x20 partials
  if (tid < 160) {
    const int a = tid % 20, j = tid / 20;
    float s = 0.f;
    #pragma unroll
    for (int i = 0; i < 25; ++i) {
      const int d = j + 8*i;
      s += zs[d] * Ww[a*D_DIM + d];
    }
    ptile[tid] = s;
  }
  __syncthreads();
  if (tid < A_DIM) {
    float s = bw[tid];
    #pragma unroll
    for (int j = 0; j < 8; ++j) s += ptile[j*20 + tid];
    red[2 + tid] = s;
  }
  __syncthreads();

  // r_s[d] = sum_a p_t[a]*Wt[d,a]; norms for c1
  float rsd = 0.f, zsd = 0.f;
  if (tid < D_DIM) {
    float acc = 0.f;
    #pragma unroll
    for (int a = 0; a < A_DIM; ++a) acc += red[2+a] * Wt[tid*A_DIM + a];
    rsd = acc; zsd = zs[tid];
    rs_out[(size_t)r*D_DIM + tid] = acc;
  }
  float a0 = rsd*rsd, a1 = zsd*zsd, a2 = rsd*zsd;
  #pragma unroll
  for (int o = 32; o > 0; o >>= 1) {
    a0 += __shfl_xor(a0, o); a1 += __shfl_xor(a1, o); a2 += __shfl_xor(a2, o);
  }
  if ((tid & 63) == 0) { red[24+wv] = a0; red[28+wv] = a1; red[32+wv] = a2; }
  __syncthreads();
  if (tid == 0) {
    const float s0 = red[24]+red[25]+red[26]+red[27];
    const float s1 = red[28]+red[29]+red[30]+red[31];
    const float s2 = red[32]+red[33]+red[34]+red[35];
    const float nr = fmaxf(sqrtf(s0), EPS_);
    const float nz = fmaxf(sqrtf(s1), EPS_);
    c1_out[r] = s2 / (nr * nz);
    rsinv_out[r] = 1.0f / nr;
  }
}

// ---------------- K4: c2 + margin loss from precomputed z_n ----------------
__global__ __launch_bounds__(64, 16) void k_c2(
    const float* __restrict__ zn_all, const float* __restrict__ rs,
    const float* __restrict__ c1, const float* __restrict__ rsinv,
    float* __restrict__ abae)
{
  const int rn = blockIdx.x;
  const int r = rn >> 1;              // NEG = 2
  const int lane = threadIdx.x;
  float s0 = 0.f, s1 = 0.f;
  if (lane < 50) {
    const float4 z4 = *reinterpret_cast<const float4*>(zn_all + (size_t)rn*D_DIM + 4*lane);
    const float4 r4 = *reinterpret_cast<const float4*>(rs + (size_t)r*D_DIM + 4*lane);
    s0 = z4.x*z4.x + z4.y*z4.y + z4.z*z4.z + z4.w*z4.w;
    s1 = z4.x*r4.x + z4.y*r4.y + z4.z*r4.z + z4.w*r4.w;
  }
  #pragma unroll
  for (int o = 32; o > 0; o >>= 1) { s0 += __shfl_xor(s0,o); s1 += __shfl_xor(s1,o); }
  if (lane == 0) {
    const float nz = fmaxf(sqrtf(s0), EPS_);
    abae[rn] = fmaxf((s1/nz)*rsinv[r] - c1[r] + 1.0f, 0.0f);
  }
}

// ---------------- K5: merged segment-sum apply + FM (one block per b) ----------------
__global__ __launch_bounds__(512) void k_aggfm(
    const int* __restrict__ cnt, const int* __restrict__ scol,
    const float* __restrict__ sval, const float* __restrict__ rs,
    const float* __restrict__ fcw, const float* __restrict__ V,
    float* __restrict__ uae, float* __restrict__ iae,
    float* __restrict__ linb, float* __restrict__ quadb)
{
  __shared__ __align__(16) float ivec[2*D_DIM];
  __shared__ float redw[8];
  __shared__ float qpart[10];
  const int b = blockIdx.x;
  const int tid = threadIdx.x, lane = tid & 63, wv = tid >> 6;

  if (tid < D_DIM) {
    int n = cnt[b]; n = n < SLOT_CAP ? n : SLOT_CAP;
    const int* cols = scol + (size_t)b*SLOT_CAP;
    const float* vals = sval + (size_t)b*SLOT_CAP;
    float acc = 0.f;
    for (int j = 0; j < n; ++j) acc += vals[j] * rs[(size_t)cols[j]*D_DIM + tid];
    ivec[tid] = acc;
    uae[(size_t)b*D_DIM + tid] = acc;
  } else if (tid >= 256 && tid < 256 + D_DIM) {
    const int t = tid - 256;
    int n = cnt[B_SZ + b]; n = n < SLOT_CAP ? n : SLOT_CAP;
    const int* cols = scol + (size_t)(B_SZ + b)*SLOT_CAP;
    const float* vals = sval + (size_t)(B_SZ + b)*SLOT_CAP;
    float acc = 0.f;
    for (int j = 0; j < n; ++j) acc += vals[j] * rs[(size_t)cols[j]*D_DIM + t];
    ivec[D_DIM + t] = acc;
    iae[(size_t)b*D_DIM + t] = acc;
  }
  __syncthreads();

  float lv = 0.f;
  if (tid < 2*D_DIM) lv = ivec[tid] * fcw[tid];
  #pragma unroll
  for (int o = 32; o > 0; o >>= 1) lv += __shfl_xor(lv, o);
  if (lane == 0) redw[wv] = lv;

  {
    const int k = wv;
    float s1 = 0.f, s2 = 0.f;
    for (int f = lane; f < 2*D_DIM; f += 64) {
      const float x = ivec[f];
      const float vk = V[f*10 + k];
      s1 += x*vk; s2 += x*x*vk*vk;
    }
    #pragma unroll
    for (int o = 32; o > 0; o >>= 1) { s1 += __shfl_xor(s1,o); s2 += __shfl_xor(s2,o); }
    if (lane == 0) qpart[k] = s1*s1 - s2;
  }
  if (wv < 2) {
    const int k = 8 + wv;
    float s1 = 0.f, s2 = 0.f;
    for (int f = lane; f < 2*D_DIM; f += 64) {
      const float x = ivec[f];
      const float vk = V[f*10 + k];
      s1 += x*vk; s2 += x*x*vk*vk;
    }
    #pragma unroll
    for (int o = 32; o > 0; o >>= 1) { s1 += __shfl_xor(s1,o); s2 += __shfl_xor(s2,o); }
    if (lane == 0) qpart[k] = s1*s1 - s2;
  }
  __syncthreads();
  if (tid == 0) {
    float lin = 0.f;
    #pragma unroll
    for (int i = 0; i < 8; ++i) lin += redw[i];
    float q = 0.f;
    #pragma unroll
    for (int i = 0; i < 10; ++i) q += qpart[i];
    linb[b] = lin; quadb[b] = q;
  }
}

// ---------------- K6: fused quad-reduce + prediction + all final scalars ----------------
__global__ __launch_bounds__(1024) void k_final2(
    const float* __restrict__ quadb, const float* __restrict__ linb,
    const float* __restrict__ fcb, const int* __restrict__ user,
    const int* __restrict__ item, const float* __restrict__ busers,
    const float* __restrict__ bitems, const float* __restrict__ label,
    const float* __restrict__ Wt, const float* __restrict__ abae,
    float* __restrict__ pred, float* __restrict__ rl, float* __restrict__ obj)
{
  __shared__ float sA[16], sB[16], sC[16];
  __shared__ float cninv[A_DIM];
  __shared__ float quad_s;
  const int tid = threadIdx.x;
  const int lane = tid & 63;
  const int wv = tid >> 6;

  float q = quadb[tid];
  #pragma unroll
  for (int o = 32; o > 0; o >>= 1) q += __shfl_xor(q, o);
  if (lane == 0) sA[wv] = q;

  if (tid < A_DIM) {
    float s = 0.f;
    for (int d = 0; d < D_DIM; ++d) { const float w = Wt[d*A_DIM + tid]; s += w*w; }
    cninv[tid] = 1.0f / fmaxf(sqrtf(s), EPS_);
  }
  __syncthreads();
  if (wv == 0) {
    float s = (lane < 16) ? sA[lane] : 0.f;
    #pragma unroll
    for (int o = 32; o > 0; o >>= 1) s += __shfl_xor(s, o);
    if (lane == 0) quad_s = s;
  }
  __syncthreads();

  const float p = 0.5f*quad_s + linb[tid] + fcb[0]
                + busers[user[tid]] + bitems[item[tid]];
  pred[tid] = p;
  const float dd = p - label[tid];
  const float myrl = dd*dd;
  rl[tid] = myrl;

  float u = 0.f;
  if (tid < 400) {
    const int a = tid / 20, c = tid % 20;
    float dot = 0.f;
    for (int d = 0; d < D_DIM; ++d) dot += Wt[d*A_DIM + a]*Wt[d*A_DIM + c];
    const float g = dot*cninv[a]*cninv[c] - (a==c ? 1.0f : 0.0f);
    u = g*g;
  }
  float js = 0.f;
  #pragma unroll
  for (int j = 0; j < 8; ++j) js += abae[tid + 1024*j];
  float ms = myrl;

  #pragma unroll
  for (int o = 32; o > 0; o >>= 1) {
    u += __shfl_xor(u,o); js += __shfl_xor(js,o); ms += __shfl_xor(ms,o);
  }
  if (lane == 0) { sA[wv] = u; sB[wv] = js; sC[wv] = ms; }
  __syncthreads();
  if (tid == 0) {
    float U = 0.f, J = 0.f, Ms = 0.f;
    for (int i = 0; i < 16; ++i) { U += sA[i]; J += sB[i]; Ms += sC[i]; }
    obj[0] = Ms/1024.0f + 0.01f*(J/8192.0f) + 0.01f*(U/400.0f);
  }
}

extern "C" void kernel_launch(void* const* d_in, const int* in_sizes, int n_in,
                              void* d_out, int out_size, void* d_ws, size_t ws_size,
                              hipStream_t stream) {
  const int*   hist   = (const int*)  d_in[0];
  const int*   neg    = (const int*)  d_in[1];
  const int*   user   = (const int*)  d_in[2];
  const int*   item   = (const int*)  d_in[3];
  const float* label  = (const float*)d_in[4];
  const int*   uidx   = (const int*)  d_in[5];
  const float* uval   = (const float*)d_in[6];
  const int*   iidx   = (const int*)  d_in[7];
  const float* ival   = (const float*)d_in[8];
  const float* emb    = (const float*)d_in[9];
  const float* Wm     = (const float*)d_in[10];
  const float* Ww     = (const float*)d_in[11];
  const float* bw     = (const float*)d_in[12];
  const float* Wt     = (const float*)d_in[13];
  const float* fcw    = (const float*)d_in[14];
  const float* fcb    = (const float*)d_in[15];
  const float* V      = (const float*)d_in[16];
  const float* busers = (const float*)d_in[17];
  const float* bitems = (const float*)d_in[18];

  float* out  = (float*)d_out;
  float* obj  = out;                       // 1
  float* rl   = out + 1;                   // 1024
  float* abae = out + 1 + B_SZ;            // 8192
  float* pred = out + 1 + B_SZ + RN_TOT;   // 1024
  float* uae  = pred + B_SZ;               // 204800
  float* iae  = uae + (size_t)B_SZ*D_DIM;  // 204800

  float* ws     = (float*)d_ws;
  float* rs     = ws;                              // R*D
  float* ys_all = rs + (size_t)R_TOT*D_DIM;        // R*D
  float* zn_all = ys_all + (size_t)R_TOT*D_DIM;    // RN*D
  float* vv_all = zn_all + (size_t)RN_TOT*D_DIM;   // R*D
  float* c1     = vv_all + (size_t)R_TOT*D_DIM;    // R
  float* rsinv  = c1 + R_TOT;                      // R
  float* linb   = rsinv + R_TOT;                   // B
  float* quadb  = linb + B_SZ;                     // B
  float* sval   = quadb + B_SZ;                    // 2*B*SLOT_CAP floats
  int*   scol   = (int*)(sval + (size_t)2*B_SZ*SLOT_CAP);   // 2*B*SLOT_CAP ints
  int*   cnt    = scol + (size_t)2*B_SZ*SLOT_CAP;           // 2*B ints
  ushort* emb_h = (ushort*)(cnt + 2*B_SZ);                  // VOCAB*D halves

  const int cast_blocks = (VOCAB_C*D_DIM/4 + 255)/256;      // 6250

  k_cast  <<<cast_blocks, 256, 0, stream>>>(emb, emb_h, cnt);
  k_means2<<<S_TOT + NBUCK_BLK, 256, 0, stream>>>(hist, neg, emb_h,
                                                  ys_all, zn_all,
                                                  uidx, uval, iidx, ival,
                                                  cnt, scol, sval);
  k_matvec<<<R_TOT/KB_RT, 256, 0, stream>>>(ys_all, Wm, vv_all);
  k_attn  <<<R_TOT, 256, 0, stream>>>(hist, emb_h, vv_all, Ww, bw, Wt, rs, c1, rsinv);
  k_c2    <<<RN_TOT, 64, 0, stream>>>(zn_all, rs, c1, rsinv, abae);
  k_aggfm <<<B_SZ, 512, 0, stream>>>(cnt, scol, sval, rs, fcw, V,
                                     uae, iae, linb, quadb);
  k_final2<<<1, 1024, 0, stream>>>(quadb, linb, fcb, user, item, busers, bitems,
                                   label, Wt, abae, pred, rl, obj);
}

// Round 10
// 360.241 us; speedup vs baseline: 2.4367x; 1.2859x over previous
//
#include <hip/hip_runtime.h>
#include <hip/hip_fp16.h>
#include <math.h>

// Problem constants (match reference)
#define R_TOT 4096
#define L_LEN 128
#define D_DIM 200
#define A_DIM 20
#define NEGK  2
#define B_SZ  1024
#define NNZ_C 20480
#define RN_TOT (R_TOT*NEGK)
#define S_TOT (R_TOT + RN_TOT)
#define VOCAB_C 32000
#define EPS_ 1e-12f
#define SLOT_CAP 64          // Poisson(20) max bin ~45; 64 is safe
#define NBUCK_BLK 160        // 160*256 = 40960 = 2*NNZ_C

__device__ __forceinline__ float4 unpack4(const uint2 u) {
  union { unsigned v; __half2 h; } c0, c1;
  c0.v = u.x; c1.v = u.y;
  const float2 f0 = __half22float2(c0.h);
  const float2 f1 = __half22float2(c1.h);
  return make_float4(f0.x, f0.y, f1.x, f1.y);
}

// ---------------- K0: cast emb -> fp16 table; block 0 also zeroes bucket counters ----------------
__global__ __launch_bounds__(256) void k_cast(
    const float* __restrict__ emb, ushort* __restrict__ emb_h, int* __restrict__ cnt)
{
  if (blockIdx.x == 0) {
    for (int i = threadIdx.x; i < 2*B_SZ; i += 256) cnt[i] = 0;
  }
  const int idx = blockIdx.x*256 + threadIdx.x;
  if (idx < (VOCAB_C*D_DIM)/4) {
    const float4 v = reinterpret_cast<const float4*>(emb)[idx];
    ushort4 o;
    o.x = __half_as_ushort(__float2half(v.x));
    o.y = __half_as_ushort(__float2half(v.y));
    o.z = __half_as_ushort(__float2half(v.z));
    o.w = __half_as_ushort(__float2half(v.w));
    reinterpret_cast<ushort4*>(emb_h)[idx] = o;
  }
}

// ---------------- K1: combined means (pos+neg, fp16) + piggybacked sparse bucketing ----------------
// Round-5 simple gather loop: manual ILP-4 unroll (rounds 7/9) spilled accumulators
// to scratch (WRITE_SIZE 270 MB vs 10 MB program writes) — let the compiler pipeline.
__global__ __launch_bounds__(256, 8) void k_means2(
    const int* __restrict__ hist, const int* __restrict__ neg,
    const ushort* __restrict__ emb_h,
    float* __restrict__ ys_all, float* __restrict__ zn_all,
    const int* __restrict__ uidx, const float* __restrict__ uval,
    const int* __restrict__ iidx, const float* __restrict__ ival,
    int* __restrict__ cnt, int* __restrict__ scol, float* __restrict__ sval)
{
  const int s = blockIdx.x;
  const int tid = threadIdx.x, lane = tid & 63, wv = tid >> 6;

  if (s >= S_TOT) {
    // ---- bucket pass: one thread per nnz entry (user then item) ----
    const int g = (s - S_TOT)*256 + tid;
    if (g < NNZ_C) {
      const int b = uidx[g];
      const int slot = atomicAdd(&cnt[b], 1);
      if (slot < SLOT_CAP) {
        scol[b*SLOT_CAP + slot] = uidx[NNZ_C + g];
        sval[b*SLOT_CAP + slot] = uval[g];
      }
    } else {
      const int g2 = g - NNZ_C;
      const int b = iidx[g2];
      const int slot = atomicAdd(&cnt[B_SZ + b], 1);
      if (slot < SLOT_CAP) {
        scol[(B_SZ + b)*SLOT_CAP + slot] = iidx[NNZ_C + g2];
        sval[(B_SZ + b)*SLOT_CAP + slot] = ival[g2];
      }
    }
    return;
  }

  __shared__ int widx[L_LEN];
  __shared__ __align__(16) float part[4][D_DIM];
  const bool is_pos = (s < R_TOT);
  const int* src = is_pos ? (hist + (size_t)s*L_LEN)
                          : (neg + (size_t)(s - R_TOT)*L_LEN);
  if (tid < L_LEN) widx[tid] = src[tid];
  __syncthreads();

  float4 acc = {0.f, 0.f, 0.f, 0.f};
  for (int l = wv; l < L_LEN; l += 4) {
    if (lane < 50) {
      const float4 v = unpack4(*reinterpret_cast<const uint2*>(
          emb_h + (size_t)widx[l]*D_DIM + 4*lane));
      acc.x += v.x; acc.y += v.y; acc.z += v.z; acc.w += v.w;
    }
  }
  if (lane < 50) *reinterpret_cast<float4*>(&part[wv][4*lane]) = acc;
  __syncthreads();
  float* dst = is_pos ? (ys_all + (size_t)s*D_DIM)
                      : (zn_all + (size_t)(s - R_TOT)*D_DIM);
  if (tid < D_DIM)
    dst[tid] = (part[0][tid] + part[1][tid] + part[2][tid] + part[3][tid]) * (1.0f/128.0f);
}

// ---------------- K2: V = Y @ Wm (16 reviews/block) ----------------
#define KB_RT 16
__global__ __launch_bounds__(256, 2) void k_matvec(
    const float* __restrict__ ys_all, const float* __restrict__ Wm,
    float* __restrict__ vv_all)
{
  __shared__ float ysl[KB_RT][D_DIM];
  const int r0 = blockIdx.x * KB_RT;
  const int tid = threadIdx.x;
  for (int i = tid; i < KB_RT*D_DIM; i += 256)
    ysl[i / D_DIM][i % D_DIM] = ys_all[(size_t)r0*D_DIM + i];
  __syncthreads();
  if (tid < D_DIM) {
    float acc[KB_RT];
    #pragma unroll
    for (int r = 0; r < KB_RT; ++r) acc[r] = 0.f;
    #pragma unroll 4
    for (int k = 0; k < D_DIM; ++k) {
      const float w = Wm[k*D_DIM + tid];
      #pragma unroll
      for (int r = 0; r < KB_RT; ++r) acc[r] += ysl[r][k] * w;
    }
    #pragma unroll
    for (int r = 0; r < KB_RT; ++r)
      vv_all[(size_t)(r0 + r)*D_DIM + tid] = acc[r];
  }
}

// ---------------- K3: dx -> softmax -> z_s -> p_t -> r_s -> c1 -> c2/abae fused epilogue ----------------
__global__ __launch_bounds__(256, 8) void k_attn(
    const int* __restrict__ hist, const ushort* __restrict__ emb_h,
    const float* __restrict__ vv_all, const float* __restrict__ Ww,
    const float* __restrict__ bw, const float* __restrict__ Wt,
    const float* __restrict__ zn_all,
    float* __restrict__ rs_out, float* __restrict__ abae)
{
  __shared__ int widx[L_LEN];
  __shared__ __align__(16) float ax[L_LEN];
  __shared__ __align__(16) float vvl[D_DIM];
  __shared__ float zs[D_DIM];
  __shared__ float ptile[160];
  __shared__ float red[44];
  const int r = blockIdx.x;
  const int tid = threadIdx.x, lane = tid & 63, wv = tid >> 6;

  if (tid < L_LEN) widx[tid] = hist[r*L_LEN + tid];
  if (tid < D_DIM) vvl[tid] = vv_all[(size_t)r*D_DIM + tid];
  __syncthreads();

  // dx[l] = e_w[l,:].v — wave-per-row, fp16 uint2 loads, butterfly
  {
    float4 v4 = {0.f,0.f,0.f,0.f};
    if (lane < 50) v4 = *reinterpret_cast<const float4*>(vvl + 4*lane);
    for (int l = wv; l < L_LEN; l += 4) {
      float a = 0.f;
      if (lane < 50) {
        const float4 e4 = unpack4(*reinterpret_cast<const uint2*>(
            emb_h + (size_t)widx[l]*D_DIM + 4*lane));
        a = e4.x*v4.x + e4.y*v4.y + e4.z*v4.z + e4.w*v4.w;
      }
      #pragma unroll
      for (int o = 32; o > 0; o >>= 1) a += __shfl_xor(a, o);
      if (lane == 0) ax[l] = a;
    }
  }
  __syncthreads();

  // softmax over 128 (wave0 reduces)
  if (tid < 64) {
    float m = fmaxf(ax[tid], ax[tid+64]);
    #pragma unroll
    for (int o = 32; o > 0; o >>= 1) m = fmaxf(m, __shfl_xor(m, o));
    if (tid == 0) red[0] = m;
  }
  __syncthreads();
  const float M = red[0];
  if (tid < L_LEN) ax[tid] = expf(ax[tid] - M);
  __syncthreads();
  if (tid < 64) {
    float s = ax[tid] + ax[tid+64];
    #pragma unroll
    for (int o = 32; o > 0; o >>= 1) s += __shfl_xor(s, o);
    if (tid == 0) red[1] = s;
  }
  __syncthreads();
  const float Sinv = 1.0f / red[1];
  if (tid < L_LEN) ax[tid] *= Sinv;
  __syncthreads();

  // z_s[d] = sum_i ax[i]*flat[128d+i]; every 4-half group is in-row & 8B-aligned
  {
    const int lh = lane & 31;
    const float4 ax4 = *reinterpret_cast<const float4*>(ax + 4*lh);
    for (int dp = wv; dp < 100; dp += 4) {
      const int d = 2*dp + (lane >> 5);
      const int f = (d << 7) + 4*lh;
      const float4 e4 = unpack4(*reinterpret_cast<const uint2*>(
          emb_h + (size_t)widx[f/200]*D_DIM + (f % 200)));
      float a = e4.x*ax4.x + e4.y*ax4.y + e4.z*ax4.z + e4.w*ax4.w;
      #pragma unroll
      for (int o = 16; o > 0; o >>= 1) a += __shfl_xor(a, o);
      if (lh == 0) zs[d] = a;
    }
  }
  __syncthreads();

  // p_t[a] = z_s . Ww[a,:] + bw[a]  — 8x20 partials
  if (tid < 160) {
    const int a = tid % 20, j = tid / 20;
    float s = 0.f;
    #pragma unroll
    for (int i = 0; i < 25; ++i) {
      const int d = j + 8*i;
      s += zs[d] * Ww[a*D_DIM + d];
    }
    ptile[tid] = s;
  }
  __syncthreads();
  if (tid < A_DIM) {
    float s = bw[tid];
    #pragma unroll
    for (int j = 0; j < 8; ++j) s += ptile[j*20 + tid];
    red[2 + tid] = s;
  }
  __syncthreads();

  // r_s[d] = sum_a p_t[a]*Wt[d,a]; then fused norms for c1 AND both c2 (z_n rows)
  float rsd = 0.f, zsd = 0.f, zn0 = 0.f, zn1 = 0.f;
  if (tid < D_DIM) {
    float acc = 0.f;
    #pragma unroll
    for (int a = 0; a < A_DIM; ++a) acc += red[2+a] * Wt[tid*A_DIM + a];
    rsd = acc; zsd = zs[tid];
    rs_out[(size_t)r*D_DIM + tid] = acc;
    zn0 = zn_all[(size_t)(2*r)*D_DIM + tid];
    zn1 = zn_all[(size_t)(2*r + 1)*D_DIM + tid];
  }
  float a0 = rsd*rsd, a1 = zsd*zsd, a2 = rsd*zsd;
  float b0 = zn0*zn0, b1 = zn0*rsd, b2 = zn1*zn1, b3 = zn1*rsd;
  #pragma unroll
  for (int o = 32; o > 0; o >>= 1) {
    a0 += __shfl_xor(a0, o); a1 += __shfl_xor(a1, o); a2 += __shfl_xor(a2, o);
    b0 += __shfl_xor(b0, o); b1 += __shfl_xor(b1, o);
    b2 += __shfl_xor(b2, o); b3 += __shfl_xor(b3, o);
  }
  if ((tid & 63) == 0) {
    red[12+wv] = a0; red[16+wv] = a1; red[20+wv] = a2;
    red[24+wv] = b0; red[28+wv] = b1; red[32+wv] = b2; red[36+wv] = b3;
  }
  __syncthreads();
  if (tid == 0) {
    const float s0 = red[12]+red[13]+red[14]+red[15];   // |r_s|^2
    const float s1 = red[16]+red[17]+red[18]+red[19];   // |z_s|^2
    const float s2 = red[20]+red[21]+red[22]+red[23];   // r_s.z_s
    const float t0 = red[24]+red[25]+red[26]+red[27];   // |zn0|^2
    const float t1 = red[28]+red[29]+red[30]+red[31];   // zn0.r_s
    const float t2 = red[32]+red[33]+red[34]+red[35];   // |zn1|^2
    const float t3 = red[36]+red[37]+red[38]+red[39];   // zn1.r_s
    const float nr = fmaxf(sqrtf(s0), EPS_);
    const float nz = fmaxf(sqrtf(s1), EPS_);
    const float c1 = s2 / (nr * nz);
    const float c2a = t1 / (fmaxf(sqrtf(t0), EPS_) * nr);
    const float c2b = t3 / (fmaxf(sqrtf(t2), EPS_) * nr);
    abae[2*r]     = fmaxf(c2a - c1 + 1.0f, 0.0f);
    abae[2*r + 1] = fmaxf(c2b - c1 + 1.0f, 0.0f);
  }
}

// ---------------- K4: merged segment-sum apply + FM (one block per b) ----------------
__global__ __launch_bounds__(512) void k_aggfm(
    const int* __restrict__ cnt, const int* __restrict__ scol,
    const float* __restrict__ sval, const float* __restrict__ rs,
    const float* __restrict__ fcw, const float* __restrict__ V,
    float* __restrict__ uae, float* __restrict__ iae,
    float* __restrict__ linb, float* __restrict__ quadb)
{
  __shared__ __align__(16) float ivec[2*D_DIM];
  __shared__ float redw[8];
  __shared__ float qpart[10];
  const int b = blockIdx.x;
  const int tid = threadIdx.x, lane = tid & 63, wv = tid >> 6;

  if (tid < D_DIM) {
    int n = cnt[b]; n = n < SLOT_CAP ? n : SLOT_CAP;
    const int* cols = scol + (size_t)b*SLOT_CAP;
    const float* vals = sval + (size_t)b*SLOT_CAP;
    float acc = 0.f;
    for (int j = 0; j < n; ++j) acc += vals[j] * rs[(size_t)cols[j]*D_DIM + tid];
    ivec[tid] = acc;
    uae[(size_t)b*D_DIM + tid] = acc;
  } else if (tid >= 256 && tid < 256 + D_DIM) {
    const int t = tid - 256;
    int n = cnt[B_SZ + b]; n = n < SLOT_CAP ? n : SLOT_CAP;
    const int* cols = scol + (size_t)(B_SZ + b)*SLOT_CAP;
    const float* vals = sval + (size_t)(B_SZ + b)*SLOT_CAP;
    float acc = 0.f;
    for (int j = 0; j < n; ++j) acc += vals[j] * rs[(size_t)cols[j]*D_DIM + t];
    ivec[D_DIM + t] = acc;
    iae[(size_t)b*D_DIM + t] = acc;
  }
  __syncthreads();

  float lv = 0.f;
  if (tid < 2*D_DIM) lv = ivec[tid] * fcw[tid];
  #pragma unroll
  for (int o = 32; o > 0; o >>= 1) lv += __shfl_xor(lv, o);
  if (lane == 0) redw[wv] = lv;

  {
    const int k = wv;
    float s1 = 0.f, s2 = 0.f;
    for (int f = lane; f < 2*D_DIM; f += 64) {
      const float x = ivec[f];
      const float vk = V[f*10 + k];
      s1 += x*vk; s2 += x*x*vk*vk;
    }
    #pragma unroll
    for (int o = 32; o > 0; o >>= 1) { s1 += __shfl_xor(s1,o); s2 += __shfl_xor(s2,o); }
    if (lane == 0) qpart[k] = s1*s1 - s2;
  }
  if (wv < 2) {
    const int k = 8 + wv;
    float s1 = 0.f, s2 = 0.f;
    for (int f = lane; f < 2*D_DIM; f += 64) {
      const float x = ivec[f];
      const float vk = V[f*10 + k];
      s1 += x*vk; s2 += x*x*vk*vk;
    }
    #pragma unroll
    for (int o = 32; o > 0; o >>= 1) { s1 += __shfl_xor(s1,o); s2 += __shfl_xor(s2,o); }
    if (lane == 0) qpart[k] = s1*s1 - s2;
  }
  __syncthreads();
  if (tid == 0) {
    float lin = 0.f;
    #pragma unroll
    for (int i = 0; i < 8; ++i) lin += redw[i];
    float q = 0.f;
    #pragma unroll
    for (int i = 0; i < 10; ++i) q += qpart[i];
    linb[b] = lin; quadb[b] = q;
  }
}

// ---------------- K5: fused quad-reduce + prediction + all final scalars ----------------
__global__ __launch_bounds__(1024) void k_final2(
    const float* __restrict__ quadb, const float* __restrict__ linb,
    const float* __restrict__ fcb, const int* __restrict__ user,
    const int* __restrict__ item, const float* __restrict__ busers,
    const float* __restrict__ bitems, const float* __restrict__ label,
    const float* __restrict__ Wt, const float* __restrict__ abae,
    float* __restrict__ pred, float* __restrict__ rl, float* __restrict__ obj)
{
  __shared__ float sA[16], sB[16], sC[16];
  __shared__ float cninv[A_DIM];
  __shared__ float quad_s;
  const int tid = threadIdx.x;
  const int lane = tid & 63;
  const int wv = tid >> 6;

  float q = quadb[tid];
  #pragma unroll
  for (int o = 32; o > 0; o >>= 1) q += __shfl_xor(q, o);
  if (lane == 0) sA[wv] = q;

  if (tid < A_DIM) {
    float s = 0.f;
    for (int d = 0; d < D_DIM; ++d) { const float w = Wt[d*A_DIM + tid]; s += w*w; }
    cninv[tid] = 1.0f / fmaxf(sqrtf(s), EPS_);
  }
  __syncthreads();
  if (wv == 0) {
    float s = (lane < 16) ? sA[lane] : 0.f;
    #pragma unroll
    for (int o = 32; o > 0; o >>= 1) s += __shfl_xor(s, o);
    if (lane == 0) quad_s = s;
  }
  __syncthreads();

  const float p = 0.5f*quad_s + linb[tid] + fcb[0]
                + busers[user[tid]] + bitems[item[tid]];
  pred[tid] = p;
  const float dd = p - label[tid];
  const float myrl = dd*dd;
  rl[tid] = myrl;

  float u = 0.f;
  if (tid < 400) {
    const int a = tid / 20, c = tid % 20;
    float dot = 0.f;
    for (int d = 0; d < D_DIM; ++d) dot += Wt[d*A_DIM + a]*Wt[d*A_DIM + c];
    const float g = dot*cninv[a]*cninv[c] - (a==c ? 1.0f : 0.0f);
    u = g*g;
  }
  float js = 0.f;
  #pragma unroll
  for (int j = 0; j < 8; ++j) js += abae[tid + 1024*j];
  float ms = myrl;

  #pragma unroll
  for (int o = 32; o > 0; o >>= 1) {
    u += __shfl_xor(u,o); js += __shfl_xor(js,o); ms += __shfl_xor(ms,o);
  }
  if (lane == 0) { sA[wv] = u; sB[wv] = js; sC[wv] = ms; }
  __syncthreads();
  if (tid == 0) {
    float U = 0.f, J = 0.f, Ms = 0.f;
    for (int i = 0; i < 16; ++i) { U += sA[i]; J += sB[i]; Ms += sC[i]; }
    obj[0] = Ms/1024.0f + 0.01f*(J/8192.0f) + 0.01f*(U/400.0f);
  }
}

extern "C" void kernel_launch(void* const* d_in, const int* in_sizes, int n_in,
                              void* d_out, int out_size, void* d_ws, size_t ws_size,
                              hipStream_t stream) {
  const int*   hist   = (const int*)  d_in[0];
  const int*   neg    = (const int*)  d_in[1];
  const int*   user   = (const int*)  d_in[2];
  const int*   item   = (const int*)  d_in[3];
  const float* label  = (const float*)d_in[4];
  const int*   uidx   = (const int*)  d_in[5];
  const float* uval   = (const float*)d_in[6];
  const int*   iidx   = (const int*)  d_in[7];
  const float* ival   = (const float*)d_in[8];
  const float* emb    = (const float*)d_in[9];
  const float* Wm     = (const float*)d_in[10];
  const float* Ww     = (const float*)d_in[11];
  const float* bw     = (const float*)d_in[12];
  const float* Wt     = (const float*)d_in[13];
  const float* fcw    = (const float*)d_in[14];
  const float* fcb    = (const float*)d_in[15];
  const float* V      = (const float*)d_in[16];
  const float* busers = (const float*)d_in[17];
  const float* bitems = (const float*)d_in[18];

  float* out  = (float*)d_out;
  float* obj  = out;                       // 1
  float* rl   = out + 1;                   // 1024
  float* abae = out + 1 + B_SZ;            // 8192
  float* pred = out + 1 + B_SZ + RN_TOT;   // 1024
  float* uae  = pred + B_SZ;               // 204800
  float* iae  = uae + (size_t)B_SZ*D_DIM;  // 204800

  float* ws     = (float*)d_ws;
  float* rs     = ws;                              // R*D
  float* ys_all = rs + (size_t)R_TOT*D_DIM;        // R*D
  float* zn_all = ys_all + (size_t)R_TOT*D_DIM;    // RN*D
  float* vv_all = zn_all + (size_t)RN_TOT*D_DIM;   // R*D
  float* linb   = vv_all + (size_t)R_TOT*D_DIM;    // B
  float* quadb  = linb + B_SZ;                     // B
  float* sval   = quadb + B_SZ;                    // 2*B*SLOT_CAP floats
  int*   scol   = (int*)(sval + (size_t)2*B_SZ*SLOT_CAP);   // 2*B*SLOT_CAP ints
  int*   cnt    = scol + (size_t)2*B_SZ*SLOT_CAP;           // 2*B ints
  ushort* emb_h = (ushort*)(cnt + 2*B_SZ);                  // VOCAB*D halves

  const int cast_blocks = (VOCAB_C*D_DIM/4 + 255)/256;      // 6250

  k_cast  <<<cast_blocks, 256, 0, stream>>>(emb, emb_h, cnt);
  k_means2<<<S_TOT + NBUCK_BLK, 256, 0, stream>>>(hist, neg, emb_h,
                                                  ys_all, zn_all,
                                                  uidx, uval, iidx, ival,
                                                  cnt, scol, sval);
  k_matvec<<<R_TOT/KB_RT, 256, 0, stream>>>(ys_all, Wm, vv_all);
  k_attn  <<<R_TOT, 256, 0, stream>>>(hist, emb_h, vv_all, Ww, bw, Wt,
                                      zn_all, rs, abae);
  k_aggfm <<<B_SZ, 512, 0, stream>>>(cnt, scol, sval, rs, fcw, V,
                                     uae, iae, linb, quadb);
  k_final2<<<1, 1024, 0, stream>>>(quadb, linb, fcb, user, item, busers, bitems,
                                   label, Wt, abae, pred, rl, obj);
}